// Round 1
// baseline (3020.809 us; speedup 1.0000x reference)
//
#include <hip/hip_runtime.h>

#define N_NODES   100000
#define N_EDGES   1600000
#define IN_DIM    128
#define HID_DIM   64
#define N_CLASSES 40

// ---------------- GEMM1: out[n,64] = x[n,128] @ W1[128,64] + b1 ----------------
__global__ __launch_bounds__(256) void gemm1_kernel(const float* __restrict__ x,
                                                    const float* __restrict__ W1,
                                                    const float* __restrict__ b1,
                                                    float* __restrict__ out) {
    __shared__ float sW[IN_DIM * HID_DIM];   // 32 KB
    __shared__ float sx[4 * IN_DIM];         // 2 KB
    for (int i = threadIdx.x; i < IN_DIM * HID_DIM; i += 256) sW[i] = W1[i];
    for (int i = threadIdx.x; i < 4 * IN_DIM; i += 256) {
        int n = blockIdx.x * 4 + i / IN_DIM;
        sx[i] = (n < N_NODES) ? x[(size_t)blockIdx.x * 4 * IN_DIM + i] : 0.f;
    }
    __syncthreads();
    int node = blockIdx.x * 4 + (threadIdx.x >> 6);
    int dim  = threadIdx.x & 63;
    if (node >= N_NODES) return;
    const float* xr = sx + (threadIdx.x >> 6) * IN_DIM;
    float acc = b1[dim];
#pragma unroll 8
    for (int k = 0; k < IN_DIM; ++k) acc = fmaf(xr[k], sW[k * HID_DIM + dim], acc);
    out[(size_t)node * HID_DIM + dim] = acc;
}

// ---------------- GEMM2: out[n,64] = relu(h[n,64]) @ W2[64,64] + b2 ----------------
__global__ __launch_bounds__(256) void gemm2_kernel(const float* __restrict__ h,
                                                    const float* __restrict__ W2,
                                                    const float* __restrict__ b2,
                                                    float* __restrict__ out) {
    __shared__ float sW[HID_DIM * HID_DIM];  // 16 KB
    __shared__ float sh[4 * HID_DIM];        // 1 KB
    for (int i = threadIdx.x; i < HID_DIM * HID_DIM; i += 256) sW[i] = W2[i];
    for (int i = threadIdx.x; i < 4 * HID_DIM; i += 256) {
        int n = blockIdx.x * 4 + i / HID_DIM;
        float v = (n < N_NODES) ? h[(size_t)blockIdx.x * 4 * HID_DIM + i] : 0.f;
        sh[i] = v > 0.f ? v : 0.f;           // fused ReLU
    }
    __syncthreads();
    int node = blockIdx.x * 4 + (threadIdx.x >> 6);
    int dim  = threadIdx.x & 63;
    if (node >= N_NODES) return;
    const float* hr = sh + (threadIdx.x >> 6) * HID_DIM;
    float acc = b2[dim];
#pragma unroll
    for (int k = 0; k < HID_DIM; ++k) acc = fmaf(hr[k], sW[k * HID_DIM + dim], acc);
    out[(size_t)node * HID_DIM + dim] = acc;
}

// ---------------- SpMM: out[row] += val * dense[col]  (COO scatter, atomics) ----------------
// 16 threads per edge, each handles one float4 (4 scalar atomics).
__global__ __launch_bounds__(256) void spmm_scatter(const int* __restrict__ row,
                                                    const int* __restrict__ col,
                                                    const float* __restrict__ val,
                                                    const float* __restrict__ dense,
                                                    float* __restrict__ out) {
    long long idx = (long long)blockIdx.x * 256 + threadIdx.x;
    int e = (int)(idx >> 4);
    int q = (int)(idx & 15);
    if (e >= N_EDGES) return;
    int   r = row[e];
    int   c = col[e];
    float v = val[e];
    const float4 src = ((const float4*)(dense + (size_t)c * HID_DIM))[q];
    float* dst = out + (size_t)r * HID_DIM + q * 4;
    atomicAdd(dst + 0, v * src.x);
    atomicAdd(dst + 1, v * src.y);
    atomicAdd(dst + 2, v * src.z);
    atomicAdd(dst + 3, v * src.w);
}

// ---------------- Classifier: logits = h @ Wc + bc; out = log_softmax(logits) ----------------
#define TNODES 64
__global__ __launch_bounds__(256) void classify_kernel(const float* __restrict__ h,
                                                       const float* __restrict__ Wc,
                                                       const float* __restrict__ bc,
                                                       float* __restrict__ out) {
    __shared__ float sW[HID_DIM * N_CLASSES];    // 2560 floats
    __shared__ float sb[N_CLASSES];
    __shared__ float sh[TNODES * HID_DIM];       // 4096 floats
    __shared__ float slog[TNODES * N_CLASSES];   // 2560 floats
    __shared__ float smax[TNODES], slse[TNODES];
    int node0 = blockIdx.x * TNODES;
    for (int i = threadIdx.x; i < HID_DIM * N_CLASSES; i += 256) sW[i] = Wc[i];
    if (threadIdx.x < N_CLASSES) sb[threadIdx.x] = bc[threadIdx.x];
    for (int i = threadIdx.x; i < TNODES * HID_DIM; i += 256) {
        int n = node0 + (i >> 6);
        sh[i] = (n < N_NODES) ? h[(size_t)node0 * HID_DIM + i] : 0.f;
    }
    __syncthreads();
    // logits
    for (int i = threadIdx.x; i < TNODES * N_CLASSES; i += 256) {
        int n = i / N_CLASSES, c = i - n * N_CLASSES;
        float acc = sb[c];
#pragma unroll
        for (int k = 0; k < HID_DIM; ++k)
            acc = fmaf(sh[n * HID_DIM + k], sW[k * N_CLASSES + c], acc);
        slog[i] = acc;
    }
    __syncthreads();
    // per-node max and log-sum-exp (threads 0..63, one node each)
    if (threadIdx.x < TNODES) {
        int n = threadIdx.x;
        float m = -1e30f;
        for (int c = 0; c < N_CLASSES; ++c) m = fmaxf(m, slog[n * N_CLASSES + c]);
        float s = 0.f;
        for (int c = 0; c < N_CLASSES; ++c) s += expf(slog[n * N_CLASSES + c] - m);
        smax[n] = m;
        slse[n] = logf(s);
    }
    __syncthreads();
    for (int i = threadIdx.x; i < TNODES * N_CLASSES; i += 256) {
        long long gi = (long long)node0 * N_CLASSES + i;
        if (gi < (long long)N_NODES * N_CLASSES) {
            int n = i / N_CLASSES;
            out[gi] = slog[i] - smax[n] - slse[n];
        }
    }
}

extern "C" void kernel_launch(void* const* d_in, const int* in_sizes, int n_in,
                              void* d_out, int out_size, void* d_ws, size_t ws_size,
                              hipStream_t stream) {
    const float* x    = (const float*)d_in[0];
    const int*   erow = (const int*)  d_in[1];
    const int*   ecol = (const int*)  d_in[2];
    const float* eval = (const float*)d_in[3];
    const float* W1   = (const float*)d_in[4];
    const float* b1   = (const float*)d_in[5];
    const float* W2   = (const float*)d_in[6];
    const float* b2   = (const float*)d_in[7];
    const float* Wc   = (const float*)d_in[8];
    const float* bc   = (const float*)d_in[9];
    float* out = (float*)d_out;

    float* bufA = (float*)d_ws;                               // support buffer [N,64]
    float* bufB = bufA + (size_t)N_NODES * HID_DIM;           // aggregate buffer [N,64]
    const size_t hbytes = (size_t)N_NODES * HID_DIM * sizeof(float);

    const int gemm_grid = (N_NODES + 3) / 4;
    const int spmm_grid = (int)(((long long)N_EDGES * 16 + 255) / 256);
    const int cls_grid  = (N_NODES + TNODES - 1) / TNODES;

    // layer 1
    gemm1_kernel<<<gemm_grid, 256, 0, stream>>>(x, W1, b1, bufA);
    hipMemsetAsync(bufB, 0, hbytes, stream);
    spmm_scatter<<<spmm_grid, 256, 0, stream>>>(erow, ecol, eval, bufA, bufB);
    // layer 2 (ReLU fused into gemm2 load)
    gemm2_kernel<<<gemm_grid, 256, 0, stream>>>(bufB, W2, b2, bufA);
    hipMemsetAsync(bufB, 0, hbytes, stream);
    spmm_scatter<<<spmm_grid, 256, 0, stream>>>(erow, ecol, eval, bufA, bufB);
    // classifier + log-softmax
    classify_kernel<<<cls_grid, 256, 0, stream>>>(bufB, Wc, bc, out);
}

// Round 2
// 631.365 us; speedup vs baseline: 4.7846x; 4.7846x over previous
//
#include <hip/hip_runtime.h>

#define N_NODES   100000
#define N_EDGES   1600000
#define IN_DIM    128
#define HID_DIM   64
#define N_CLASSES 40
#define NP1       (N_NODES + 1)          // 100001 scan elements
#define SCAN_BLKS ((NP1 + 255) / 256)    // 391

// ---------------- GEMM1: out[n,64] = x[n,128] @ W1[128,64] + b1 ----------------
__global__ __launch_bounds__(256) void gemm1_kernel(const float* __restrict__ x,
                                                    const float* __restrict__ W1,
                                                    const float* __restrict__ b1,
                                                    float* __restrict__ out) {
    __shared__ float sW[IN_DIM * HID_DIM];   // 32 KB
    __shared__ float sx[4 * IN_DIM];         // 2 KB
    for (int i = threadIdx.x; i < IN_DIM * HID_DIM; i += 256) sW[i] = W1[i];
    for (int i = threadIdx.x; i < 4 * IN_DIM; i += 256) {
        int n = blockIdx.x * 4 + i / IN_DIM;
        sx[i] = (n < N_NODES) ? x[(size_t)blockIdx.x * 4 * IN_DIM + i] : 0.f;
    }
    __syncthreads();
    int node = blockIdx.x * 4 + (threadIdx.x >> 6);
    int dim  = threadIdx.x & 63;
    if (node >= N_NODES) return;
    const float* xr = sx + (threadIdx.x >> 6) * IN_DIM;
    float acc = b1[dim];
#pragma unroll 8
    for (int k = 0; k < IN_DIM; ++k) acc = fmaf(xr[k], sW[k * HID_DIM + dim], acc);
    out[(size_t)node * HID_DIM + dim] = acc;
}

// ---------------- GEMM2: out[n,64] = relu(h[n,64]) @ W2[64,64] + b2 ----------------
__global__ __launch_bounds__(256) void gemm2_kernel(const float* __restrict__ h,
                                                    const float* __restrict__ W2,
                                                    const float* __restrict__ b2,
                                                    float* __restrict__ out) {
    __shared__ float sW[HID_DIM * HID_DIM];  // 16 KB
    __shared__ float sh[4 * HID_DIM];        // 1 KB
    for (int i = threadIdx.x; i < HID_DIM * HID_DIM; i += 256) sW[i] = W2[i];
    for (int i = threadIdx.x; i < 4 * HID_DIM; i += 256) {
        int n = blockIdx.x * 4 + i / HID_DIM;
        float v = (n < N_NODES) ? h[(size_t)blockIdx.x * 4 * HID_DIM + i] : 0.f;
        sh[i] = v > 0.f ? v : 0.f;           // fused ReLU
    }
    __syncthreads();
    int node = blockIdx.x * 4 + (threadIdx.x >> 6);
    int dim  = threadIdx.x & 63;
    if (node >= N_NODES) return;
    const float* hr = sh + (threadIdx.x >> 6) * HID_DIM;
    float acc = b2[dim];
#pragma unroll
    for (int k = 0; k < HID_DIM; ++k) acc = fmaf(hr[k], sW[k * HID_DIM + dim], acc);
    out[(size_t)node * HID_DIM + dim] = acc;
}

// ---------------- CSR build ----------------
__global__ __launch_bounds__(256) void hist_kernel(const int* __restrict__ row,
                                                   int* __restrict__ counts) {
    int e = blockIdx.x * 256 + threadIdx.x;
    if (e < N_EDGES) atomicAdd(&counts[row[e]], 1);
}

// per-block exclusive scan (256 elems) + block totals
__global__ __launch_bounds__(256) void scan1_kernel(const int* __restrict__ counts,
                                                    int* __restrict__ rowptr,
                                                    int* __restrict__ blksum) {
    __shared__ int s[256];
    int i = blockIdx.x * 256 + threadIdx.x;
    int v = (i < NP1) ? counts[i] : 0;
    s[threadIdx.x] = v;
    __syncthreads();
    for (int off = 1; off < 256; off <<= 1) {
        int t = (threadIdx.x >= off) ? s[threadIdx.x - off] : 0;
        __syncthreads();
        s[threadIdx.x] += t;
        __syncthreads();
    }
    if (i < NP1) rowptr[i] = s[threadIdx.x] - v;   // exclusive
    if (threadIdx.x == 255) blksum[blockIdx.x] = s[255];
}

// single-block exclusive scan of the 391 block sums
__global__ __launch_bounds__(512) void scan2_kernel(int* __restrict__ blksum) {
    __shared__ int s[512];
    int v = (threadIdx.x < SCAN_BLKS) ? blksum[threadIdx.x] : 0;
    s[threadIdx.x] = v;
    __syncthreads();
    for (int off = 1; off < 512; off <<= 1) {
        int t = (threadIdx.x >= off) ? s[threadIdx.x - off] : 0;
        __syncthreads();
        s[threadIdx.x] += t;
        __syncthreads();
    }
    if (threadIdx.x < SCAN_BLKS) blksum[threadIdx.x] = s[threadIdx.x] - v;
}

__global__ __launch_bounds__(256) void scan3_kernel(int* __restrict__ rowptr,
                                                    const int* __restrict__ blksum) {
    int i = blockIdx.x * 256 + threadIdx.x;
    if (i < NP1) rowptr[i] += blksum[blockIdx.x];
}

__global__ __launch_bounds__(256) void scatter_kernel(const int* __restrict__ row,
                                                      const int* __restrict__ col,
                                                      const float* __restrict__ val,
                                                      const int* __restrict__ rowptr,
                                                      int* __restrict__ fill,
                                                      int* __restrict__ scol,
                                                      float* __restrict__ sval) {
    int e = blockIdx.x * 256 + threadIdx.x;
    if (e >= N_EDGES) return;
    int r = row[e];
    int pos = rowptr[r] + atomicAdd(&fill[r], 1);
    scol[pos] = col[e];
    sval[pos] = val[e];
}

// ---------------- SpMM (CSR): one wave per row, lane = dim ----------------
__global__ __launch_bounds__(256) void spmm_csr(const int* __restrict__ rowptr,
                                                const int* __restrict__ scol,
                                                const float* __restrict__ sval,
                                                const float* __restrict__ dense,
                                                float* __restrict__ out) {
    int r = blockIdx.x * 4 + (threadIdx.x >> 6);
    if (r >= N_NODES) return;
    int lane = threadIdx.x & 63;
    int rs = __builtin_amdgcn_readfirstlane(rowptr[r]);
    int re = __builtin_amdgcn_readfirstlane(rowptr[r + 1]);
    float acc = 0.f;
    int e = rs;
    for (; e + 3 < re; e += 4) {
        int   c0 = scol[e + 0], c1 = scol[e + 1], c2 = scol[e + 2], c3 = scol[e + 3];
        float v0 = sval[e + 0], v1 = sval[e + 1], v2 = sval[e + 2], v3 = sval[e + 3];
        float d0 = dense[(size_t)c0 * HID_DIM + lane];
        float d1 = dense[(size_t)c1 * HID_DIM + lane];
        float d2 = dense[(size_t)c2 * HID_DIM + lane];
        float d3 = dense[(size_t)c3 * HID_DIM + lane];
        acc = fmaf(v0, d0, acc);
        acc = fmaf(v1, d1, acc);
        acc = fmaf(v2, d2, acc);
        acc = fmaf(v3, d3, acc);
    }
    for (; e < re; ++e) {
        int c = scol[e];
        float v = sval[e];
        acc = fmaf(v, dense[(size_t)c * HID_DIM + lane], acc);
    }
    out[(size_t)r * HID_DIM + lane] = acc;
}

// ---------------- Classifier: logits = h @ Wc + bc; out = log_softmax(logits) ----------------
#define TNODES 64
__global__ __launch_bounds__(256) void classify_kernel(const float* __restrict__ h,
                                                       const float* __restrict__ Wc,
                                                       const float* __restrict__ bc,
                                                       float* __restrict__ out) {
    __shared__ float sW[HID_DIM * N_CLASSES];
    __shared__ float sb[N_CLASSES];
    __shared__ float sh[TNODES * HID_DIM];
    __shared__ float slog[TNODES * N_CLASSES];
    __shared__ float smax[TNODES], slse[TNODES];
    int node0 = blockIdx.x * TNODES;
    for (int i = threadIdx.x; i < HID_DIM * N_CLASSES; i += 256) sW[i] = Wc[i];
    if (threadIdx.x < N_CLASSES) sb[threadIdx.x] = bc[threadIdx.x];
    for (int i = threadIdx.x; i < TNODES * HID_DIM; i += 256) {
        int n = node0 + (i >> 6);
        sh[i] = (n < N_NODES) ? h[(size_t)node0 * HID_DIM + i] : 0.f;
    }
    __syncthreads();
    for (int i = threadIdx.x; i < TNODES * N_CLASSES; i += 256) {
        int n = i / N_CLASSES, c = i - n * N_CLASSES;
        float acc = sb[c];
#pragma unroll
        for (int k = 0; k < HID_DIM; ++k)
            acc = fmaf(sh[n * HID_DIM + k], sW[k * N_CLASSES + c], acc);
        slog[i] = acc;
    }
    __syncthreads();
    if (threadIdx.x < TNODES) {
        int n = threadIdx.x;
        float m = -1e30f;
        for (int c = 0; c < N_CLASSES; ++c) m = fmaxf(m, slog[n * N_CLASSES + c]);
        float s = 0.f;
        for (int c = 0; c < N_CLASSES; ++c) s += expf(slog[n * N_CLASSES + c] - m);
        smax[n] = m;
        slse[n] = logf(s);
    }
    __syncthreads();
    for (int i = threadIdx.x; i < TNODES * N_CLASSES; i += 256) {
        long long gi = (long long)node0 * N_CLASSES + i;
        if (gi < (long long)N_NODES * N_CLASSES) {
            int n = i / N_CLASSES;
            out[gi] = slog[i] - smax[n] - slse[n];
        }
    }
}

extern "C" void kernel_launch(void* const* d_in, const int* in_sizes, int n_in,
                              void* d_out, int out_size, void* d_ws, size_t ws_size,
                              hipStream_t stream) {
    const float* x    = (const float*)d_in[0];
    const int*   erow = (const int*)  d_in[1];
    const int*   ecol = (const int*)  d_in[2];
    const float* eval = (const float*)d_in[3];
    const float* W1   = (const float*)d_in[4];
    const float* b1   = (const float*)d_in[5];
    const float* W2   = (const float*)d_in[6];
    const float* b2   = (const float*)d_in[7];
    const float* Wc   = (const float*)d_in[8];
    const float* bc   = (const float*)d_in[9];
    float* out = (float*)d_out;

    // ---- workspace layout (4-byte units) ----
    char* ws = (char*)d_ws;
    size_t off = 0;
    auto alloc = [&](size_t bytes) { char* p = ws + off; off += (bytes + 255) & ~(size_t)255; return p; };
    float* bufA   = (float*)alloc((size_t)N_NODES * HID_DIM * sizeof(float)); // 25.6 MB
    float* bufB   = (float*)alloc((size_t)N_NODES * HID_DIM * sizeof(float)); // 25.6 MB
    int*   counts = (int*)  alloc(NP1 * sizeof(int));
    int*   rowptr = (int*)  alloc(NP1 * sizeof(int));
    int*   blksum = (int*)  alloc(512 * sizeof(int));
    int*   fill   = (int*)  alloc(N_NODES * sizeof(int));
    int*   scol   = (int*)  alloc((size_t)N_EDGES * sizeof(int));             // 6.4 MB
    float* sval   = (float*)alloc((size_t)N_EDGES * sizeof(float));           // 6.4 MB

    const int egrid     = (N_EDGES + 255) / 256;
    const int gemm_grid = (N_NODES + 3) / 4;
    const int cls_grid  = (N_NODES + TNODES - 1) / TNODES;

    // ---- build CSR (reused by both spmm layers) ----
    hipMemsetAsync(counts, 0, NP1 * sizeof(int), stream);
    hipMemsetAsync(fill,   0, N_NODES * sizeof(int), stream);
    hist_kernel<<<egrid, 256, 0, stream>>>(erow, counts);
    scan1_kernel<<<SCAN_BLKS, 256, 0, stream>>>(counts, rowptr, blksum);
    scan2_kernel<<<1, 512, 0, stream>>>(blksum);
    scan3_kernel<<<SCAN_BLKS, 256, 0, stream>>>(rowptr, blksum);
    scatter_kernel<<<egrid, 256, 0, stream>>>(erow, ecol, eval, rowptr, fill, scol, sval);

    // ---- layer 1 ----
    gemm1_kernel<<<gemm_grid, 256, 0, stream>>>(x, W1, b1, bufA);
    spmm_csr<<<gemm_grid, 256, 0, stream>>>(rowptr, scol, sval, bufA, bufB);
    // ---- layer 2 (ReLU fused into gemm2 load) ----
    gemm2_kernel<<<gemm_grid, 256, 0, stream>>>(bufB, W2, b2, bufA);
    spmm_csr<<<gemm_grid, 256, 0, stream>>>(rowptr, scol, sval, bufA, bufB);
    // ---- classifier + log-softmax ----
    classify_kernel<<<cls_grid, 256, 0, stream>>>(bufB, Wc, bc, out);
}

// Round 3
// 476.230 us; speedup vs baseline: 6.3432x; 1.3258x over previous
//
#include <hip/hip_runtime.h>

#define N_NODES   100000
#define N_EDGES   1600000
#define IN_DIM    128
#define HID_DIM   64
#define N_CLASSES 40
#define NP1       (N_NODES + 1)          // 100001 scan elements
#define SCAN_BLKS ((NP1 + 255) / 256)    // 391

typedef __attribute__((ext_vector_type(8))) short bf16x8;
typedef __attribute__((ext_vector_type(4))) float f32x4;

__device__ inline short f2bf(float f) {
    unsigned u = __float_as_uint(f);
    unsigned r = (u + 0x7FFFu + ((u >> 16) & 1u)) >> 16;   // round-to-nearest-even
    return (short)r;
}

// ---------------- weight prep: W1[128,64] -> W1t bf16 [64][128]; W2[64,64] -> W2t [64][64] ----------------
__global__ __launch_bounds__(256) void prep_weights(const float* __restrict__ W1,
                                                    const float* __restrict__ W2,
                                                    short* __restrict__ W1t,
                                                    short* __restrict__ W2t) {
    for (int i = blockIdx.x * 256 + threadIdx.x; i < IN_DIM * HID_DIM; i += gridDim.x * 256) {
        int n = i >> 7, k = i & 127;                 // i = n*128 + k
        W1t[i] = f2bf(W1[k * HID_DIM + n]);
    }
    for (int i = blockIdx.x * 256 + threadIdx.x; i < HID_DIM * HID_DIM; i += gridDim.x * 256) {
        int n = i >> 6, k = i & 63;                  // i = n*64 + k
        W2t[i] = f2bf(W2[k * HID_DIM + n]);
    }
}

// ---------------- GEMM1 (MFMA): out[n,64] = x[n,128] @ W1 + b1 ----------------
// wave handles 16 nodes x 64 dims; A from global fp32->bf16 in regs; B from W1t (L1-resident).
__global__ __launch_bounds__(256) void gemm1_mfma(const float* __restrict__ x,
                                                  const short* __restrict__ W1t,
                                                  const float* __restrict__ b1,
                                                  float* __restrict__ out) {
    int wave = threadIdx.x >> 6;
    int lane = threadIdx.x & 63;
    int node0 = blockIdx.x * 64 + wave * 16;
    if (node0 >= N_NODES) return;                    // 100000 % 16 == 0: full waves only
    int m = lane & 15;
    int q = lane >> 4;
    const float* xrow = x + (size_t)(node0 + m) * IN_DIM;
    f32x4 acc0 = {0,0,0,0}, acc1 = {0,0,0,0}, acc2 = {0,0,0,0}, acc3 = {0,0,0,0};
#pragma unroll
    for (int kb = 0; kb < 4; ++kb) {
        int k0 = kb * 32 + q * 8;
        float4 a0 = *(const float4*)(xrow + k0);
        float4 a1 = *(const float4*)(xrow + k0 + 4);
        bf16x8 af;
        af[0]=f2bf(a0.x); af[1]=f2bf(a0.y); af[2]=f2bf(a0.z); af[3]=f2bf(a0.w);
        af[4]=f2bf(a1.x); af[5]=f2bf(a1.y); af[6]=f2bf(a1.z); af[7]=f2bf(a1.w);
        bf16x8 bf0 = *(const bf16x8*)(W1t + ( 0 + m) * IN_DIM + k0);
        bf16x8 bf1 = *(const bf16x8*)(W1t + (16 + m) * IN_DIM + k0);
        bf16x8 bf2 = *(const bf16x8*)(W1t + (32 + m) * IN_DIM + k0);
        bf16x8 bf3 = *(const bf16x8*)(W1t + (48 + m) * IN_DIM + k0);
        acc0 = __builtin_amdgcn_mfma_f32_16x16x32_bf16(af, bf0, acc0, 0, 0, 0);
        acc1 = __builtin_amdgcn_mfma_f32_16x16x32_bf16(af, bf1, acc1, 0, 0, 0);
        acc2 = __builtin_amdgcn_mfma_f32_16x16x32_bf16(af, bf2, acc2, 0, 0, 0);
        acc3 = __builtin_amdgcn_mfma_f32_16x16x32_bf16(af, bf3, acc3, 0, 0, 0);
    }
    f32x4 accs[4] = {acc0, acc1, acc2, acc3};
#pragma unroll
    for (int t = 0; t < 4; ++t) {
        float bias = b1[t * 16 + m];
#pragma unroll
        for (int r = 0; r < 4; ++r) {
            int node = node0 + q * 4 + r;            // C/D: col=lane&15, row=q*4+r
            out[(size_t)node * HID_DIM + t * 16 + m] = accs[t][r] + bias;
        }
    }
}

// ---------------- GEMM2 (MFMA): out[n,64] = relu(h[n,64]) @ W2 + b2 ----------------
__global__ __launch_bounds__(256) void gemm2_mfma(const float* __restrict__ h,
                                                  const short* __restrict__ W2t,
                                                  const float* __restrict__ b2,
                                                  float* __restrict__ out) {
    int wave = threadIdx.x >> 6;
    int lane = threadIdx.x & 63;
    int node0 = blockIdx.x * 64 + wave * 16;
    if (node0 >= N_NODES) return;
    int m = lane & 15;
    int q = lane >> 4;
    const float* hrow = h + (size_t)(node0 + m) * HID_DIM;
    f32x4 acc0 = {0,0,0,0}, acc1 = {0,0,0,0}, acc2 = {0,0,0,0}, acc3 = {0,0,0,0};
#pragma unroll
    for (int kb = 0; kb < 2; ++kb) {
        int k0 = kb * 32 + q * 8;
        float4 a0 = *(const float4*)(hrow + k0);
        float4 a1 = *(const float4*)(hrow + k0 + 4);
        bf16x8 af;
        af[0]=f2bf(fmaxf(a0.x,0.f)); af[1]=f2bf(fmaxf(a0.y,0.f));
        af[2]=f2bf(fmaxf(a0.z,0.f)); af[3]=f2bf(fmaxf(a0.w,0.f));
        af[4]=f2bf(fmaxf(a1.x,0.f)); af[5]=f2bf(fmaxf(a1.y,0.f));
        af[6]=f2bf(fmaxf(a1.z,0.f)); af[7]=f2bf(fmaxf(a1.w,0.f));
        bf16x8 bf0 = *(const bf16x8*)(W2t + ( 0 + m) * HID_DIM + k0);
        bf16x8 bf1 = *(const bf16x8*)(W2t + (16 + m) * HID_DIM + k0);
        bf16x8 bf2 = *(const bf16x8*)(W2t + (32 + m) * HID_DIM + k0);
        bf16x8 bf3 = *(const bf16x8*)(W2t + (48 + m) * HID_DIM + k0);
        acc0 = __builtin_amdgcn_mfma_f32_16x16x32_bf16(af, bf0, acc0, 0, 0, 0);
        acc1 = __builtin_amdgcn_mfma_f32_16x16x32_bf16(af, bf1, acc1, 0, 0, 0);
        acc2 = __builtin_amdgcn_mfma_f32_16x16x32_bf16(af, bf2, acc2, 0, 0, 0);
        acc3 = __builtin_amdgcn_mfma_f32_16x16x32_bf16(af, bf3, acc3, 0, 0, 0);
    }
    f32x4 accs[4] = {acc0, acc1, acc2, acc3};
#pragma unroll
    for (int t = 0; t < 4; ++t) {
        float bias = b2[t * 16 + m];
#pragma unroll
        for (int r = 0; r < 4; ++r) {
            int node = node0 + q * 4 + r;
            out[(size_t)node * HID_DIM + t * 16 + m] = accs[t][r] + bias;
        }
    }
}

// ---------------- CSR build ----------------
__global__ __launch_bounds__(256) void hist_kernel(const int* __restrict__ row,
                                                   int* __restrict__ counts) {
    int e = blockIdx.x * 256 + threadIdx.x;
    if (e < N_EDGES) atomicAdd(&counts[row[e]], 1);
}

__global__ __launch_bounds__(256) void scan1_kernel(const int* __restrict__ counts,
                                                    int* __restrict__ rowptr,
                                                    int* __restrict__ blksum) {
    __shared__ int s[256];
    int i = blockIdx.x * 256 + threadIdx.x;
    int v = (i < NP1) ? counts[i] : 0;
    s[threadIdx.x] = v;
    __syncthreads();
    for (int off = 1; off < 256; off <<= 1) {
        int t = (threadIdx.x >= off) ? s[threadIdx.x - off] : 0;
        __syncthreads();
        s[threadIdx.x] += t;
        __syncthreads();
    }
    if (i < NP1) rowptr[i] = s[threadIdx.x] - v;   // exclusive
    if (threadIdx.x == 255) blksum[blockIdx.x] = s[255];
}

__global__ __launch_bounds__(512) void scan2_kernel(int* __restrict__ blksum) {
    __shared__ int s[512];
    int v = (threadIdx.x < SCAN_BLKS) ? blksum[threadIdx.x] : 0;
    s[threadIdx.x] = v;
    __syncthreads();
    for (int off = 1; off < 512; off <<= 1) {
        int t = (threadIdx.x >= off) ? s[threadIdx.x - off] : 0;
        __syncthreads();
        s[threadIdx.x] += t;
        __syncthreads();
    }
    if (threadIdx.x < SCAN_BLKS) blksum[threadIdx.x] = s[threadIdx.x] - v;
}

__global__ __launch_bounds__(256) void scan3_kernel(int* __restrict__ rowptr,
                                                    const int* __restrict__ blksum) {
    int i = blockIdx.x * 256 + threadIdx.x;
    if (i < NP1) rowptr[i] += blksum[blockIdx.x];
}

// scatter with interleaved (col, val) 8-byte payload; cursor = atomicSub on degree histogram
__global__ __launch_bounds__(256) void scatter_kernel(const int* __restrict__ row,
                                                      const int* __restrict__ col,
                                                      const float* __restrict__ val,
                                                      const int* __restrict__ rowptr,
                                                      int* __restrict__ counts,
                                                      int2* __restrict__ ecv) {
    int e = blockIdx.x * 256 + threadIdx.x;
    if (e >= N_EDGES) return;
    int r = row[e];
    int pos = rowptr[r] + atomicSub(&counts[r], 1) - 1;
    ecv[pos] = make_int2(col[e], __float_as_int(val[e]));
}

// ---------------- SpMM (CSR): one wave per row, lane = dim ----------------
__global__ __launch_bounds__(256) void spmm_csr(const int* __restrict__ rowptr,
                                                const int2* __restrict__ ecv,
                                                const float* __restrict__ dense,
                                                float* __restrict__ out) {
    int r = blockIdx.x * 4 + (threadIdx.x >> 6);
    if (r >= N_NODES) return;
    int lane = threadIdx.x & 63;
    int rs = __builtin_amdgcn_readfirstlane(rowptr[r]);
    int re = __builtin_amdgcn_readfirstlane(rowptr[r + 1]);
    float acc = 0.f;
    int e = rs;
    for (; e + 3 < re; e += 4) {
        int2 e0 = ecv[e + 0], e1 = ecv[e + 1], e2 = ecv[e + 2], e3 = ecv[e + 3];
        float d0 = dense[(size_t)e0.x * HID_DIM + lane];
        float d1 = dense[(size_t)e1.x * HID_DIM + lane];
        float d2 = dense[(size_t)e2.x * HID_DIM + lane];
        float d3 = dense[(size_t)e3.x * HID_DIM + lane];
        acc = fmaf(__int_as_float(e0.y), d0, acc);
        acc = fmaf(__int_as_float(e1.y), d1, acc);
        acc = fmaf(__int_as_float(e2.y), d2, acc);
        acc = fmaf(__int_as_float(e3.y), d3, acc);
    }
    for (; e < re; ++e) {
        int2 ee = ecv[e];
        acc = fmaf(__int_as_float(ee.y), dense[(size_t)ee.x * HID_DIM + lane], acc);
    }
    out[(size_t)r * HID_DIM + lane] = acc;
}

// ---------------- Classifier: logits = h @ Wc + bc; out = log_softmax(logits) ----------------
#define TNODES 64
__global__ __launch_bounds__(256) void classify_kernel(const float* __restrict__ h,
                                                       const float* __restrict__ Wc,
                                                       const float* __restrict__ bc,
                                                       float* __restrict__ out) {
    __shared__ float sW[HID_DIM * N_CLASSES];
    __shared__ float sb[N_CLASSES];
    __shared__ float sh[TNODES * HID_DIM];
    __shared__ float slog[TNODES * N_CLASSES];
    __shared__ float smax[TNODES], slse[TNODES];
    int node0 = blockIdx.x * TNODES;
    for (int i = threadIdx.x; i < HID_DIM * N_CLASSES; i += 256) sW[i] = Wc[i];
    if (threadIdx.x < N_CLASSES) sb[threadIdx.x] = bc[threadIdx.x];
    for (int i = threadIdx.x; i < TNODES * HID_DIM; i += 256) {
        int n = node0 + (i >> 6);
        sh[i] = (n < N_NODES) ? h[(size_t)node0 * HID_DIM + i] : 0.f;
    }
    __syncthreads();
    for (int i = threadIdx.x; i < TNODES * N_CLASSES; i += 256) {
        int n = i / N_CLASSES, c = i - n * N_CLASSES;
        float acc = sb[c];
#pragma unroll
        for (int k = 0; k < HID_DIM; ++k)
            acc = fmaf(sh[n * HID_DIM + k], sW[k * N_CLASSES + c], acc);
        slog[i] = acc;
    }
    __syncthreads();
    if (threadIdx.x < TNODES) {
        int n = threadIdx.x;
        float m = -1e30f;
        for (int c = 0; c < N_CLASSES; ++c) m = fmaxf(m, slog[n * N_CLASSES + c]);
        float s = 0.f;
        for (int c = 0; c < N_CLASSES; ++c) s += expf(slog[n * N_CLASSES + c] - m);
        smax[n] = m;
        slse[n] = logf(s);
    }
    __syncthreads();
    for (int i = threadIdx.x; i < TNODES * N_CLASSES; i += 256) {
        long long gi = (long long)node0 * N_CLASSES + i;
        if (gi < (long long)N_NODES * N_CLASSES) {
            int n = i / N_CLASSES;
            out[gi] = slog[i] - smax[n] - slse[n];
        }
    }
}

extern "C" void kernel_launch(void* const* d_in, const int* in_sizes, int n_in,
                              void* d_out, int out_size, void* d_ws, size_t ws_size,
                              hipStream_t stream) {
    const float* x    = (const float*)d_in[0];
    const int*   erow = (const int*)  d_in[1];
    const int*   ecol = (const int*)  d_in[2];
    const float* eval = (const float*)d_in[3];
    const float* W1   = (const float*)d_in[4];
    const float* b1   = (const float*)d_in[5];
    const float* W2   = (const float*)d_in[6];
    const float* b2   = (const float*)d_in[7];
    const float* Wc   = (const float*)d_in[8];
    const float* bc   = (const float*)d_in[9];
    float* out = (float*)d_out;

    // ---- workspace layout ----
    char* ws = (char*)d_ws;
    size_t off = 0;
    auto alloc = [&](size_t bytes) { char* p = ws + off; off += (bytes + 255) & ~(size_t)255; return p; };
    float* bufA   = (float*)alloc((size_t)N_NODES * HID_DIM * sizeof(float)); // 25.6 MB
    float* bufB   = (float*)alloc((size_t)N_NODES * HID_DIM * sizeof(float)); // 25.6 MB
    int*   counts = (int*)  alloc(NP1 * sizeof(int));
    int*   rowptr = (int*)  alloc(NP1 * sizeof(int));
    int*   blksum = (int*)  alloc(512 * sizeof(int));
    int2*  ecv    = (int2*) alloc((size_t)N_EDGES * sizeof(int2));            // 12.8 MB
    short* W1t    = (short*)alloc((size_t)IN_DIM * HID_DIM * sizeof(short));
    short* W2t    = (short*)alloc((size_t)HID_DIM * HID_DIM * sizeof(short));

    const int egrid     = (N_EDGES + 255) / 256;
    const int tile_grid = (N_NODES + 63) / 64;     // 1563
    const int spmm_grid = (N_NODES + 3) / 4;

    // ---- build CSR (reused by both spmm layers) + weight prep ----
    hipMemsetAsync(counts, 0, NP1 * sizeof(int), stream);
    prep_weights<<<32, 256, 0, stream>>>(W1, W2, W1t, W2t);
    hist_kernel<<<egrid, 256, 0, stream>>>(erow, counts);
    scan1_kernel<<<SCAN_BLKS, 256, 0, stream>>>(counts, rowptr, blksum);
    scan2_kernel<<<1, 512, 0, stream>>>(blksum);
    scan3_kernel<<<SCAN_BLKS, 256, 0, stream>>>(rowptr, blksum);
    scatter_kernel<<<egrid, 256, 0, stream>>>(erow, ecol, eval, rowptr, counts, ecv);

    // ---- layer 1 ----
    gemm1_mfma<<<tile_grid, 256, 0, stream>>>(x, W1t, b1, bufA);
    spmm_csr<<<spmm_grid, 256, 0, stream>>>(rowptr, ecv, bufA, bufB);
    // ---- layer 2 (ReLU fused into gemm2 A-load) ----
    gemm2_mfma<<<tile_grid, 256, 0, stream>>>(bufB, W2t, b2, bufA);
    spmm_csr<<<spmm_grid, 256, 0, stream>>>(rowptr, ecv, bufA, bufB);
    // ---- classifier + log-softmax ----
    classify_kernel<<<tile_grid, 256, 0, stream>>>(bufB, Wc, bc, out);
}

// Round 4
// 371.488 us; speedup vs baseline: 8.1317x; 1.2820x over previous
//
#include <hip/hip_runtime.h>

#define N_NODES   100000
#define N_EDGES   1600000
#define IN_DIM    128
#define HID_DIM   64
#define N_CLASSES 40

#define NBUCK 782          // ceil(100000 / 128) coarse buckets, bucket = row >> 7
#define BCAP  2560         // bucket capacity (mean 2048, sigma ~45 -> 11 sigma headroom)
#define EPB   6400         // edges per block in pass A; 250 * 6400 == N_EDGES exactly

typedef __attribute__((ext_vector_type(8))) short bf16x8;
typedef __attribute__((ext_vector_type(4))) float f32x4;

__device__ inline short f2bf(float f) {
    unsigned u = __float_as_uint(f);
    unsigned r = (u + 0x7FFFu + ((u >> 16) & 1u)) >> 16;   // round-to-nearest-even
    return (short)r;
}

// ---------------- weight prep: W1[128,64] -> W1t bf16 [64][128]; W2[64,64] -> W2t [64][64] ----------------
__global__ __launch_bounds__(256) void prep_weights(const float* __restrict__ W1,
                                                    const float* __restrict__ W2,
                                                    short* __restrict__ W1t,
                                                    short* __restrict__ W2t) {
    for (int i = blockIdx.x * 256 + threadIdx.x; i < IN_DIM * HID_DIM; i += gridDim.x * 256) {
        int n = i >> 7, k = i & 127;
        W1t[i] = f2bf(W1[k * HID_DIM + n]);
    }
    for (int i = blockIdx.x * 256 + threadIdx.x; i < HID_DIM * HID_DIM; i += gridDim.x * 256) {
        int n = i >> 6, k = i & 63;
        W2t[i] = f2bf(W2[k * HID_DIM + n]);
    }
}

// ---------------- GEMM1 (MFMA): out[n,64] = x[n,128] @ W1 + b1 ----------------
__global__ __launch_bounds__(256) void gemm1_mfma(const float* __restrict__ x,
                                                  const short* __restrict__ W1t,
                                                  const float* __restrict__ b1,
                                                  float* __restrict__ out) {
    int wave = threadIdx.x >> 6;
    int lane = threadIdx.x & 63;
    int node0 = blockIdx.x * 64 + wave * 16;
    if (node0 >= N_NODES) return;
    int m = lane & 15;
    int q = lane >> 4;
    const float* xrow = x + (size_t)(node0 + m) * IN_DIM;
    f32x4 acc0 = {0,0,0,0}, acc1 = {0,0,0,0}, acc2 = {0,0,0,0}, acc3 = {0,0,0,0};
#pragma unroll
    for (int kb = 0; kb < 4; ++kb) {
        int k0 = kb * 32 + q * 8;
        float4 a0 = *(const float4*)(xrow + k0);
        float4 a1 = *(const float4*)(xrow + k0 + 4);
        bf16x8 af;
        af[0]=f2bf(a0.x); af[1]=f2bf(a0.y); af[2]=f2bf(a0.z); af[3]=f2bf(a0.w);
        af[4]=f2bf(a1.x); af[5]=f2bf(a1.y); af[6]=f2bf(a1.z); af[7]=f2bf(a1.w);
        bf16x8 bf0 = *(const bf16x8*)(W1t + ( 0 + m) * IN_DIM + k0);
        bf16x8 bf1 = *(const bf16x8*)(W1t + (16 + m) * IN_DIM + k0);
        bf16x8 bf2 = *(const bf16x8*)(W1t + (32 + m) * IN_DIM + k0);
        bf16x8 bf3 = *(const bf16x8*)(W1t + (48 + m) * IN_DIM + k0);
        acc0 = __builtin_amdgcn_mfma_f32_16x16x32_bf16(af, bf0, acc0, 0, 0, 0);
        acc1 = __builtin_amdgcn_mfma_f32_16x16x32_bf16(af, bf1, acc1, 0, 0, 0);
        acc2 = __builtin_amdgcn_mfma_f32_16x16x32_bf16(af, bf2, acc2, 0, 0, 0);
        acc3 = __builtin_amdgcn_mfma_f32_16x16x32_bf16(af, bf3, acc3, 0, 0, 0);
    }
    f32x4 accs[4] = {acc0, acc1, acc2, acc3};
#pragma unroll
    for (int t = 0; t < 4; ++t) {
        float bias = b1[t * 16 + m];
#pragma unroll
        for (int r = 0; r < 4; ++r) {
            int node = node0 + q * 4 + r;            // C/D: col=lane&15, row=q*4+r
            out[(size_t)node * HID_DIM + t * 16 + m] = accs[t][r] + bias;
        }
    }
}

// ---------------- GEMM2 (MFMA): out[n,64] = relu(h[n,64]) @ W2 + b2 ----------------
__global__ __launch_bounds__(256) void gemm2_mfma(const float* __restrict__ h,
                                                  const short* __restrict__ W2t,
                                                  const float* __restrict__ b2,
                                                  float* __restrict__ out) {
    int wave = threadIdx.x >> 6;
    int lane = threadIdx.x & 63;
    int node0 = blockIdx.x * 64 + wave * 16;
    if (node0 >= N_NODES) return;
    int m = lane & 15;
    int q = lane >> 4;
    const float* hrow = h + (size_t)(node0 + m) * HID_DIM;
    f32x4 acc0 = {0,0,0,0}, acc1 = {0,0,0,0}, acc2 = {0,0,0,0}, acc3 = {0,0,0,0};
#pragma unroll
    for (int kb = 0; kb < 2; ++kb) {
        int k0 = kb * 32 + q * 8;
        float4 a0 = *(const float4*)(hrow + k0);
        float4 a1 = *(const float4*)(hrow + k0 + 4);
        bf16x8 af;
        af[0]=f2bf(fmaxf(a0.x,0.f)); af[1]=f2bf(fmaxf(a0.y,0.f));
        af[2]=f2bf(fmaxf(a0.z,0.f)); af[3]=f2bf(fmaxf(a0.w,0.f));
        af[4]=f2bf(fmaxf(a1.x,0.f)); af[5]=f2bf(fmaxf(a1.y,0.f));
        af[6]=f2bf(fmaxf(a1.z,0.f)); af[7]=f2bf(fmaxf(a1.w,0.f));
        bf16x8 bf0 = *(const bf16x8*)(W2t + ( 0 + m) * HID_DIM + k0);
        bf16x8 bf1 = *(const bf16x8*)(W2t + (16 + m) * HID_DIM + k0);
        bf16x8 bf2 = *(const bf16x8*)(W2t + (32 + m) * HID_DIM + k0);
        bf16x8 bf3 = *(const bf16x8*)(W2t + (48 + m) * HID_DIM + k0);
        acc0 = __builtin_amdgcn_mfma_f32_16x16x32_bf16(af, bf0, acc0, 0, 0, 0);
        acc1 = __builtin_amdgcn_mfma_f32_16x16x32_bf16(af, bf1, acc1, 0, 0, 0);
        acc2 = __builtin_amdgcn_mfma_f32_16x16x32_bf16(af, bf2, acc2, 0, 0, 0);
        acc3 = __builtin_amdgcn_mfma_f32_16x16x32_bf16(af, bf3, acc3, 0, 0, 0);
    }
    f32x4 accs[4] = {acc0, acc1, acc2, acc3};
#pragma unroll
    for (int t = 0; t < 4; ++t) {
        float bias = b2[t * 16 + m];
#pragma unroll
        for (int r = 0; r < 4; ++r) {
            int node = node0 + q * 4 + r;
            out[(size_t)node * HID_DIM + t * 16 + m] = accs[t][r] + bias;
        }
    }
}

// ---------------- Pass A: partition edges into 782 coarse buckets (row >> 7) ----------------
// Local row (7 bits) packed into bits [17..23] of col word; col < 2^17.
__global__ __launch_bounds__(256) void part_a(const int* __restrict__ erow,
                                              const int* __restrict__ ecol,
                                              const float* __restrict__ eval,
                                              int* __restrict__ bcnt,
                                              int2* __restrict__ tmp) {
    __shared__ int srow[EPB];        // 25.6 KB
    __shared__ int hist[NBUCK];      // 3.1 KB
    __shared__ int gbase[NBUCK];
    __shared__ int cur[NBUCK];
    int e0 = blockIdx.x * EPB;
    for (int i = threadIdx.x; i < NBUCK; i += 256) { hist[i] = 0; cur[i] = 0; }
    __syncthreads();
    for (int i = threadIdx.x; i < EPB; i += 256) {
        int e = e0 + i;
        int r = (e < N_EDGES) ? erow[e] : -1;
        srow[i] = r;
        if (r >= 0) atomicAdd(&hist[r >> 7], 1);
    }
    __syncthreads();
    for (int i = threadIdx.x; i < NBUCK; i += 256) {
        int n = hist[i];
        gbase[i] = n ? atomicAdd(&bcnt[i], n) : 0;   // one global atomic per (block,bucket)
    }
    __syncthreads();
    for (int i = threadIdx.x; i < EPB; i += 256) {
        int r = srow[i];
        if (r < 0) continue;
        int e = e0 + i;
        int b = r >> 7;
        int slot = gbase[b] + atomicAdd(&cur[b], 1);
        if (slot < BCAP)
            tmp[(size_t)b * BCAP + slot] =
                make_int2(((r & 127) << 17) | ecol[e], __float_as_int(eval[e]));
    }
}

// ---------------- Pass B: sort each bucket by local row in LDS, emit rowmeta ----------------
__global__ __launch_bounds__(256) void part_b(const int* __restrict__ bcnt,
                                              int2* __restrict__ tmp,
                                              int2* __restrict__ rowmeta) {
    __shared__ int2 ein[BCAP];       // 20 KB
    __shared__ int2 eout[BCAP];      // 20 KB
    __shared__ int hist[128], basep[128], cur[128], scan[128];
    int b = blockIdx.x;
    int nb = bcnt[b]; if (nb > BCAP) nb = BCAP;
    for (int i = threadIdx.x; i < nb; i += 256) ein[i] = tmp[(size_t)b * BCAP + i];
    if (threadIdx.x < 128) { hist[threadIdx.x] = 0; cur[threadIdx.x] = 0; }
    __syncthreads();
    for (int i = threadIdx.x; i < nb; i += 256)
        atomicAdd(&hist[(ein[i].x >> 17) & 127], 1);
    __syncthreads();
    if (threadIdx.x < 128) scan[threadIdx.x] = hist[threadIdx.x];
    __syncthreads();
    for (int off = 1; off < 128; off <<= 1) {
        int t = 0;
        if (threadIdx.x < 128 && threadIdx.x >= off) t = scan[threadIdx.x - off];
        __syncthreads();
        if (threadIdx.x < 128) scan[threadIdx.x] += t;
        __syncthreads();
    }
    if (threadIdx.x < 128) basep[threadIdx.x] = scan[threadIdx.x] - hist[threadIdx.x];
    __syncthreads();
    for (int i = threadIdx.x; i < nb; i += 256) {
        int lr = (ein[i].x >> 17) & 127;
        int p = basep[lr] + atomicAdd(&cur[lr], 1);
        eout[p] = make_int2(ein[i].x & 0x1FFFF, ein[i].y);
    }
    __syncthreads();
    for (int i = threadIdx.x; i < nb; i += 256) tmp[(size_t)b * BCAP + i] = eout[i];
    if (threadIdx.x < 128) {
        int r = b * 128 + threadIdx.x;
        if (r < N_NODES)
            rowmeta[r] = make_int2(b * BCAP + basep[threadIdx.x], hist[threadIdx.x]);
    }
}

// ---------------- SpMM (bucketed CSR): one wave per row, lane = dim ----------------
__global__ __launch_bounds__(256) void spmm_csr(const int2* __restrict__ rowmeta,
                                                const int2* __restrict__ ecv,
                                                const float* __restrict__ dense,
                                                float* __restrict__ out) {
    int r = blockIdx.x * 4 + (threadIdx.x >> 6);
    if (r >= N_NODES) return;
    int lane = threadIdx.x & 63;
    int2 meta = rowmeta[r];
    int rs  = __builtin_amdgcn_readfirstlane(meta.x);
    int re  = rs + __builtin_amdgcn_readfirstlane(meta.y);
    float acc = 0.f;
    int e = rs;
    for (; e + 3 < re; e += 4) {
        int2 e0 = ecv[e + 0], e1 = ecv[e + 1], e2 = ecv[e + 2], e3 = ecv[e + 3];
        float d0 = dense[(size_t)e0.x * HID_DIM + lane];
        float d1 = dense[(size_t)e1.x * HID_DIM + lane];
        float d2 = dense[(size_t)e2.x * HID_DIM + lane];
        float d3 = dense[(size_t)e3.x * HID_DIM + lane];
        acc = fmaf(__int_as_float(e0.y), d0, acc);
        acc = fmaf(__int_as_float(e1.y), d1, acc);
        acc = fmaf(__int_as_float(e2.y), d2, acc);
        acc = fmaf(__int_as_float(e3.y), d3, acc);
    }
    for (; e < re; ++e) {
        int2 ee = ecv[e];
        acc = fmaf(__int_as_float(ee.y), dense[(size_t)ee.x * HID_DIM + lane], acc);
    }
    out[(size_t)r * HID_DIM + lane] = acc;
}

// ---------------- Classifier: logits = h @ Wc + bc; out = log_softmax(logits) ----------------
#define TNODES 64
__global__ __launch_bounds__(256) void classify_kernel(const float* __restrict__ h,
                                                       const float* __restrict__ Wc,
                                                       const float* __restrict__ bc,
                                                       float* __restrict__ out) {
    __shared__ float sW[HID_DIM * N_CLASSES];
    __shared__ float sb[N_CLASSES];
    __shared__ float sh[TNODES * HID_DIM];
    __shared__ float slog[TNODES * N_CLASSES];
    __shared__ float smax[TNODES], slse[TNODES];
    int node0 = blockIdx.x * TNODES;
    for (int i = threadIdx.x; i < HID_DIM * N_CLASSES; i += 256) sW[i] = Wc[i];
    if (threadIdx.x < N_CLASSES) sb[threadIdx.x] = bc[threadIdx.x];
    for (int i = threadIdx.x; i < TNODES * HID_DIM; i += 256) {
        int n = node0 + (i >> 6);
        sh[i] = (n < N_NODES) ? h[(size_t)node0 * HID_DIM + i] : 0.f;
    }
    __syncthreads();
    for (int i = threadIdx.x; i < TNODES * N_CLASSES; i += 256) {
        int n = i / N_CLASSES, c = i - n * N_CLASSES;
        float acc = sb[c];
#pragma unroll
        for (int k = 0; k < HID_DIM; ++k)
            acc = fmaf(sh[n * HID_DIM + k], sW[k * N_CLASSES + c], acc);
        slog[i] = acc;
    }
    __syncthreads();
    if (threadIdx.x < TNODES) {
        int n = threadIdx.x;
        float m = -1e30f;
        for (int c = 0; c < N_CLASSES; ++c) m = fmaxf(m, slog[n * N_CLASSES + c]);
        float s = 0.f;
        for (int c = 0; c < N_CLASSES; ++c) s += expf(slog[n * N_CLASSES + c] - m);
        smax[n] = m;
        slse[n] = logf(s);
    }
    __syncthreads();
    for (int i = threadIdx.x; i < TNODES * N_CLASSES; i += 256) {
        long long gi = (long long)node0 * N_CLASSES + i;
        if (gi < (long long)N_NODES * N_CLASSES) {
            int n = i / N_CLASSES;
            out[gi] = slog[i] - smax[n] - slse[n];
        }
    }
}

extern "C" void kernel_launch(void* const* d_in, const int* in_sizes, int n_in,
                              void* d_out, int out_size, void* d_ws, size_t ws_size,
                              hipStream_t stream) {
    const float* x    = (const float*)d_in[0];
    const int*   erow = (const int*)  d_in[1];
    const int*   ecol = (const int*)  d_in[2];
    const float* eval = (const float*)d_in[3];
    const float* W1   = (const float*)d_in[4];
    const float* b1   = (const float*)d_in[5];
    const float* W2   = (const float*)d_in[6];
    const float* b2   = (const float*)d_in[7];
    const float* Wc   = (const float*)d_in[8];
    const float* bc   = (const float*)d_in[9];
    float* out = (float*)d_out;

    // ---- workspace layout ----
    char* ws = (char*)d_ws;
    size_t off = 0;
    auto alloc = [&](size_t bytes) { char* p = ws + off; off += (bytes + 255) & ~(size_t)255; return p; };
    float* bufA    = (float*)alloc((size_t)N_NODES * HID_DIM * sizeof(float)); // 25.6 MB
    float* bufB    = (float*)alloc((size_t)N_NODES * HID_DIM * sizeof(float)); // 25.6 MB
    int2*  tmp     = (int2*) alloc((size_t)NBUCK * BCAP * sizeof(int2));       // 16.0 MB
    int2*  rowmeta = (int2*) alloc((size_t)N_NODES * sizeof(int2));            // 0.8 MB
    int*   bcnt    = (int*)  alloc(NBUCK * sizeof(int));
    short* W1t     = (short*)alloc((size_t)IN_DIM * HID_DIM * sizeof(short));
    short* W2t     = (short*)alloc((size_t)HID_DIM * HID_DIM * sizeof(short));

    const int tile_grid = (N_NODES + 63) / 64;     // 1563
    const int spmm_grid = (N_NODES + 3) / 4;
    const int grid_a    = (N_EDGES + EPB - 1) / EPB;   // 250

    // ---- build bucketed CSR (reused by both spmm layers) + weight prep ----
    hipMemsetAsync(bcnt, 0, NBUCK * sizeof(int), stream);
    prep_weights<<<32, 256, 0, stream>>>(W1, W2, W1t, W2t);
    part_a<<<grid_a, 256, 0, stream>>>(erow, ecol, eval, bcnt, tmp);
    part_b<<<NBUCK, 256, 0, stream>>>(bcnt, tmp, rowmeta);

    // ---- layer 1 ----
    gemm1_mfma<<<tile_grid, 256, 0, stream>>>(x, W1t, b1, bufA);
    spmm_csr<<<spmm_grid, 256, 0, stream>>>(rowmeta, tmp, bufA, bufB);
    // ---- layer 2 (ReLU fused into gemm2 A-load) ----
    gemm2_mfma<<<tile_grid, 256, 0, stream>>>(bufB, W2t, b2, bufA);
    spmm_csr<<<spmm_grid, 256, 0, stream>>>(rowmeta, tmp, bufA, bufB);
    // ---- classifier + log-softmax ----
    classify_kernel<<<tile_grid, 256, 0, stream>>>(bufB, Wc, bc, out);
}

// Round 5
// 301.415 us; speedup vs baseline: 10.0221x; 1.2325x over previous
//
#include <hip/hip_runtime.h>

#define N_NODES   100000
#define N_EDGES   1600000
#define IN_DIM    128
#define HID_DIM   64
#define N_CLASSES 40
#define NCPAD     48       // classes padded to 3 MFMA tiles

#define NBUCK 782          // ceil(100000 / 128) coarse buckets, bucket = row >> 7
#define BCAP  2560         // bucket capacity (mean 2048, sigma ~45 -> 11 sigma headroom)
#define EPB   6400         // edges per block in pass A; 250 * 6400 == N_EDGES exactly

typedef __attribute__((ext_vector_type(8))) short bf16x8;
typedef __attribute__((ext_vector_type(4))) float f32x4;

__device__ inline short f2bf(float f) {
    unsigned u = __float_as_uint(f);
    unsigned r = (u + 0x7FFFu + ((u >> 16) & 1u)) >> 16;   // round-to-nearest-even
    return (short)r;
}
__device__ inline float bf2f(unsigned short s) {
    return __uint_as_float(((unsigned)s) << 16);
}

// ---------------- weight prep ----------------
// W1[128,64] -> W1t bf16 [64][128]; W2[64,64] -> W2t [64][64]; Wc[64,40] -> Wct [48][64] (zero-padded)
__global__ __launch_bounds__(256) void prep_weights(const float* __restrict__ W1,
                                                    const float* __restrict__ W2,
                                                    const float* __restrict__ Wc,
                                                    short* __restrict__ W1t,
                                                    short* __restrict__ W2t,
                                                    short* __restrict__ Wct) {
    for (int i = blockIdx.x * 256 + threadIdx.x; i < IN_DIM * HID_DIM; i += gridDim.x * 256) {
        int n = i >> 7, k = i & 127;
        W1t[i] = f2bf(W1[k * HID_DIM + n]);
    }
    for (int i = blockIdx.x * 256 + threadIdx.x; i < HID_DIM * HID_DIM; i += gridDim.x * 256) {
        int n = i >> 6, k = i & 63;
        W2t[i] = f2bf(W2[k * HID_DIM + n]);
    }
    for (int i = blockIdx.x * 256 + threadIdx.x; i < NCPAD * HID_DIM; i += gridDim.x * 256) {
        int c = i >> 6, k = i & 63;
        Wct[i] = (c < N_CLASSES) ? f2bf(Wc[k * N_CLASSES + c]) : 0;
    }
}

// ---------------- GEMM1 (MFMA): hbf[n,64] = bf16(x[n,128] @ W1 + b1) ----------------
__global__ __launch_bounds__(256) void gemm1_mfma(const float* __restrict__ x,
                                                  const short* __restrict__ W1t,
                                                  const float* __restrict__ b1,
                                                  unsigned short* __restrict__ out) {
    int wave = threadIdx.x >> 6;
    int lane = threadIdx.x & 63;
    int node0 = blockIdx.x * 64 + wave * 16;
    if (node0 >= N_NODES) return;
    int m = lane & 15;
    int q = lane >> 4;
    const float* xrow = x + (size_t)(node0 + m) * IN_DIM;
    f32x4 acc0 = {0,0,0,0}, acc1 = {0,0,0,0}, acc2 = {0,0,0,0}, acc3 = {0,0,0,0};
#pragma unroll
    for (int kb = 0; kb < 4; ++kb) {
        int k0 = kb * 32 + q * 8;
        float4 a0 = *(const float4*)(xrow + k0);
        float4 a1 = *(const float4*)(xrow + k0 + 4);
        bf16x8 af;
        af[0]=f2bf(a0.x); af[1]=f2bf(a0.y); af[2]=f2bf(a0.z); af[3]=f2bf(a0.w);
        af[4]=f2bf(a1.x); af[5]=f2bf(a1.y); af[6]=f2bf(a1.z); af[7]=f2bf(a1.w);
        bf16x8 bf0 = *(const bf16x8*)(W1t + ( 0 + m) * IN_DIM + k0);
        bf16x8 bf1 = *(const bf16x8*)(W1t + (16 + m) * IN_DIM + k0);
        bf16x8 bf2 = *(const bf16x8*)(W1t + (32 + m) * IN_DIM + k0);
        bf16x8 bf3 = *(const bf16x8*)(W1t + (48 + m) * IN_DIM + k0);
        acc0 = __builtin_amdgcn_mfma_f32_16x16x32_bf16(af, bf0, acc0, 0, 0, 0);
        acc1 = __builtin_amdgcn_mfma_f32_16x16x32_bf16(af, bf1, acc1, 0, 0, 0);
        acc2 = __builtin_amdgcn_mfma_f32_16x16x32_bf16(af, bf2, acc2, 0, 0, 0);
        acc3 = __builtin_amdgcn_mfma_f32_16x16x32_bf16(af, bf3, acc3, 0, 0, 0);
    }
    f32x4 accs[4] = {acc0, acc1, acc2, acc3};
#pragma unroll
    for (int t = 0; t < 4; ++t) {
        float bias = b1[t * 16 + m];
#pragma unroll
        for (int r = 0; r < 4; ++r) {
            int node = node0 + q * 4 + r;            // C/D: col=lane&15, row=q*4+r
            out[(size_t)node * HID_DIM + t * 16 + m] = (unsigned short)f2bf(accs[t][r] + bias);
        }
    }
}

// ---------------- GEMM2 (MFMA): hbf_out[n,64] = bf16(relu(hbf[n,64]) @ W2 + b2) ----------------
__global__ __launch_bounds__(256) void gemm2_mfma(const unsigned short* __restrict__ h,
                                                  const short* __restrict__ W2t,
                                                  const float* __restrict__ b2,
                                                  unsigned short* __restrict__ out) {
    int wave = threadIdx.x >> 6;
    int lane = threadIdx.x & 63;
    int node0 = blockIdx.x * 64 + wave * 16;
    if (node0 >= N_NODES) return;
    int m = lane & 15;
    int q = lane >> 4;
    const unsigned short* hrow = h + (size_t)(node0 + m) * HID_DIM;
    f32x4 acc0 = {0,0,0,0}, acc1 = {0,0,0,0}, acc2 = {0,0,0,0}, acc3 = {0,0,0,0};
#pragma unroll
    for (int kb = 0; kb < 2; ++kb) {
        int k0 = kb * 32 + q * 8;
        bf16x8 af = *(const bf16x8*)(hrow + k0);
#pragma unroll
        for (int j = 0; j < 8; ++j)
            af[j] = ((unsigned short)af[j] & 0x8000u) ? 0 : af[j];   // bf16 ReLU: negative -> 0
        bf16x8 bf0 = *(const bf16x8*)(W2t + ( 0 + m) * HID_DIM + k0);
        bf16x8 bf1 = *(const bf16x8*)(W2t + (16 + m) * HID_DIM + k0);
        bf16x8 bf2 = *(const bf16x8*)(W2t + (32 + m) * HID_DIM + k0);
        bf16x8 bf3 = *(const bf16x8*)(W2t + (48 + m) * HID_DIM + k0);
        acc0 = __builtin_amdgcn_mfma_f32_16x16x32_bf16(af, bf0, acc0, 0, 0, 0);
        acc1 = __builtin_amdgcn_mfma_f32_16x16x32_bf16(af, bf1, acc1, 0, 0, 0);
        acc2 = __builtin_amdgcn_mfma_f32_16x16x32_bf16(af, bf2, acc2, 0, 0, 0);
        acc3 = __builtin_amdgcn_mfma_f32_16x16x32_bf16(af, bf3, acc3, 0, 0, 0);
    }
    f32x4 accs[4] = {acc0, acc1, acc2, acc3};
#pragma unroll
    for (int t = 0; t < 4; ++t) {
        float bias = b2[t * 16 + m];
#pragma unroll
        for (int r = 0; r < 4; ++r) {
            int node = node0 + q * 4 + r;
            out[(size_t)node * HID_DIM + t * 16 + m] = (unsigned short)f2bf(accs[t][r] + bias);
        }
    }
}

// ---------------- Pass A: partition edges into 782 coarse buckets (row >> 7) ----------------
__global__ __launch_bounds__(256) void part_a(const int* __restrict__ erow,
                                              const int* __restrict__ ecol,
                                              const float* __restrict__ eval,
                                              int* __restrict__ bcnt,
                                              int2* __restrict__ tmp) {
    __shared__ int srow[EPB];        // 25.6 KB
    __shared__ int hist[NBUCK];
    __shared__ int gbase[NBUCK];
    __shared__ int cur[NBUCK];
    int e0 = blockIdx.x * EPB;
    for (int i = threadIdx.x; i < NBUCK; i += 256) { hist[i] = 0; cur[i] = 0; }
    __syncthreads();
    for (int i = threadIdx.x; i < EPB; i += 256) {
        int e = e0 + i;
        int r = (e < N_EDGES) ? erow[e] : -1;
        srow[i] = r;
        if (r >= 0) atomicAdd(&hist[r >> 7], 1);
    }
    __syncthreads();
    for (int i = threadIdx.x; i < NBUCK; i += 256) {
        int n = hist[i];
        gbase[i] = n ? atomicAdd(&bcnt[i], n) : 0;
    }
    __syncthreads();
    for (int i = threadIdx.x; i < EPB; i += 256) {
        int r = srow[i];
        if (r < 0) continue;
        int e = e0 + i;
        int b = r >> 7;
        int slot = gbase[b] + atomicAdd(&cur[b], 1);
        if (slot < BCAP)
            tmp[(size_t)b * BCAP + slot] =
                make_int2(((r & 127) << 17) | ecol[e], __float_as_int(eval[e]));
    }
}

// ---------------- Pass B: sort each bucket by local row in LDS, emit rowmeta ----------------
__global__ __launch_bounds__(256) void part_b(const int* __restrict__ bcnt,
                                              int2* __restrict__ tmp,
                                              int2* __restrict__ rowmeta) {
    __shared__ int2 ein[BCAP];       // 20 KB
    __shared__ int2 eout[BCAP];      // 20 KB
    __shared__ int hist[128], basep[128], cur[128], scan[128];
    int b = blockIdx.x;
    int nb = bcnt[b]; if (nb > BCAP) nb = BCAP;
    for (int i = threadIdx.x; i < nb; i += 256) ein[i] = tmp[(size_t)b * BCAP + i];
    if (threadIdx.x < 128) { hist[threadIdx.x] = 0; cur[threadIdx.x] = 0; }
    __syncthreads();
    for (int i = threadIdx.x; i < nb; i += 256)
        atomicAdd(&hist[(ein[i].x >> 17) & 127], 1);
    __syncthreads();
    if (threadIdx.x < 128) scan[threadIdx.x] = hist[threadIdx.x];
    __syncthreads();
    for (int off = 1; off < 128; off <<= 1) {
        int t = 0;
        if (threadIdx.x < 128 && threadIdx.x >= off) t = scan[threadIdx.x - off];
        __syncthreads();
        if (threadIdx.x < 128) scan[threadIdx.x] += t;
        __syncthreads();
    }
    if (threadIdx.x < 128) basep[threadIdx.x] = scan[threadIdx.x] - hist[threadIdx.x];
    __syncthreads();
    for (int i = threadIdx.x; i < nb; i += 256) {
        int lr = (ein[i].x >> 17) & 127;
        int p = basep[lr] + atomicAdd(&cur[lr], 1);
        eout[p] = make_int2(ein[i].x & 0x1FFFF, ein[i].y);
    }
    __syncthreads();
    for (int i = threadIdx.x; i < nb; i += 256) tmp[(size_t)b * BCAP + i] = eout[i];
    if (threadIdx.x < 128) {
        int r = b * 128 + threadIdx.x;
        if (r < N_NODES)
            rowmeta[r] = make_int2(b * BCAP + basep[threadIdx.x], hist[threadIdx.x]);
    }
}

// ---------------- SpMM (bucketed CSR, bf16 dense): one wave per row, lane = dim ----------------
__global__ __launch_bounds__(256) void spmm_csr(const int2* __restrict__ rowmeta,
                                                const int2* __restrict__ ecv,
                                                const unsigned short* __restrict__ dense,
                                                unsigned short* __restrict__ out) {
    int r = blockIdx.x * 4 + (threadIdx.x >> 6);
    if (r >= N_NODES) return;
    int lane = threadIdx.x & 63;
    int2 meta = rowmeta[r];
    int rs  = __builtin_amdgcn_readfirstlane(meta.x);
    int re  = rs + __builtin_amdgcn_readfirstlane(meta.y);
    float acc = 0.f;
    int e = rs;
    for (; e + 3 < re; e += 4) {
        int2 e0 = ecv[e + 0], e1 = ecv[e + 1], e2 = ecv[e + 2], e3 = ecv[e + 3];
        float d0 = bf2f(dense[(size_t)e0.x * HID_DIM + lane]);
        float d1 = bf2f(dense[(size_t)e1.x * HID_DIM + lane]);
        float d2 = bf2f(dense[(size_t)e2.x * HID_DIM + lane]);
        float d3 = bf2f(dense[(size_t)e3.x * HID_DIM + lane]);
        acc = fmaf(__int_as_float(e0.y), d0, acc);
        acc = fmaf(__int_as_float(e1.y), d1, acc);
        acc = fmaf(__int_as_float(e2.y), d2, acc);
        acc = fmaf(__int_as_float(e3.y), d3, acc);
    }
    for (; e < re; ++e) {
        int2 ee = ecv[e];
        acc = fmaf(__int_as_float(ee.y), bf2f(dense[(size_t)ee.x * HID_DIM + lane]), acc);
    }
    out[(size_t)r * HID_DIM + lane] = (unsigned short)f2bf(acc);
}

// ---------------- Classifier (MFMA): out = log_softmax(h @ Wc + bc) ----------------
#define SLOGW 49
__global__ __launch_bounds__(256) void classify_mfma(const unsigned short* __restrict__ h,
                                                     const short* __restrict__ Wct,
                                                     const float* __restrict__ bc,
                                                     float* __restrict__ out) {
    __shared__ float slog[64 * SLOGW];           // 12.5 KB, stride 49 breaks bank pathology
    __shared__ float smax[64], slse[64];
    int wave = threadIdx.x >> 6;
    int lane = threadIdx.x & 63;
    int node0 = blockIdx.x * 64;
    int wnode0 = node0 + wave * 16;
    int m = lane & 15;
    int q = lane >> 4;
    int arow = wnode0 + m; if (arow >= N_NODES) arow = N_NODES - 1;   // clamp, keep barrier-safe
    const unsigned short* hrow = h + (size_t)arow * HID_DIM;
    f32x4 acc0 = {0,0,0,0}, acc1 = {0,0,0,0}, acc2 = {0,0,0,0};
#pragma unroll
    for (int kb = 0; kb < 2; ++kb) {
        int k0 = kb * 32 + q * 8;
        bf16x8 af = *(const bf16x8*)(hrow + k0);
        bf16x8 bf0 = *(const bf16x8*)(Wct + ( 0 + m) * HID_DIM + k0);
        bf16x8 bf1 = *(const bf16x8*)(Wct + (16 + m) * HID_DIM + k0);
        bf16x8 bf2 = *(const bf16x8*)(Wct + (32 + m) * HID_DIM + k0);
        acc0 = __builtin_amdgcn_mfma_f32_16x16x32_bf16(af, bf0, acc0, 0, 0, 0);
        acc1 = __builtin_amdgcn_mfma_f32_16x16x32_bf16(af, bf1, acc1, 0, 0, 0);
        acc2 = __builtin_amdgcn_mfma_f32_16x16x32_bf16(af, bf2, acc2, 0, 0, 0);
    }
    f32x4 accs[3] = {acc0, acc1, acc2};
#pragma unroll
    for (int t = 0; t < 3; ++t) {
        int cls = t * 16 + m;
        float bias = (cls < N_CLASSES) ? bc[cls] : 0.f;
#pragma unroll
        for (int r = 0; r < 4; ++r) {
            int nl = wave * 16 + q * 4 + r;          // node-local index in block
            slog[nl * SLOGW + cls] = accs[t][r] + bias;
        }
    }
    __syncthreads();
    if (threadIdx.x < 64) {
        int nl = threadIdx.x;
        float mx = -1e30f;
        for (int c = 0; c < N_CLASSES; ++c) mx = fmaxf(mx, slog[nl * SLOGW + c]);
        float s = 0.f;
        for (int c = 0; c < N_CLASSES; ++c) s += expf(slog[nl * SLOGW + c] - mx);
        smax[nl] = mx;
        slse[nl] = logf(s);
    }
    __syncthreads();
    for (int i = threadIdx.x; i < 64 * N_CLASSES; i += 256) {
        long long gi = (long long)node0 * N_CLASSES + i;
        if (gi < (long long)N_NODES * N_CLASSES) {
            int nl = i / N_CLASSES, c = i - nl * N_CLASSES;
            out[gi] = slog[nl * SLOGW + c] - smax[nl] - slse[nl];
        }
    }
}

extern "C" void kernel_launch(void* const* d_in, const int* in_sizes, int n_in,
                              void* d_out, int out_size, void* d_ws, size_t ws_size,
                              hipStream_t stream) {
    const float* x    = (const float*)d_in[0];
    const int*   erow = (const int*)  d_in[1];
    const int*   ecol = (const int*)  d_in[2];
    const float* eval = (const float*)d_in[3];
    const float* W1   = (const float*)d_in[4];
    const float* b1   = (const float*)d_in[5];
    const float* W2   = (const float*)d_in[6];
    const float* b2   = (const float*)d_in[7];
    const float* Wc   = (const float*)d_in[8];
    const float* bc   = (const float*)d_in[9];
    float* out = (float*)d_out;

    // ---- workspace layout ----
    char* ws = (char*)d_ws;
    size_t off = 0;
    auto alloc = [&](size_t bytes) { char* p = ws + off; off += (bytes + 255) & ~(size_t)255; return p; };
    unsigned short* bufA = (unsigned short*)alloc((size_t)N_NODES * HID_DIM * sizeof(short)); // 12.8 MB
    unsigned short* bufB = (unsigned short*)alloc((size_t)N_NODES * HID_DIM * sizeof(short)); // 12.8 MB
    int2*  tmp     = (int2*) alloc((size_t)NBUCK * BCAP * sizeof(int2));       // 16.0 MB
    int2*  rowmeta = (int2*) alloc((size_t)N_NODES * sizeof(int2));            // 0.8 MB
    int*   bcnt    = (int*)  alloc(NBUCK * sizeof(int));
    short* W1t     = (short*)alloc((size_t)IN_DIM * HID_DIM * sizeof(short));
    short* W2t     = (short*)alloc((size_t)HID_DIM * HID_DIM * sizeof(short));
    short* Wct     = (short*)alloc((size_t)NCPAD * HID_DIM * sizeof(short));

    const int tile_grid = (N_NODES + 63) / 64;     // 1563
    const int spmm_grid = (N_NODES + 3) / 4;
    const int grid_a    = (N_EDGES + EPB - 1) / EPB;   // 250

    // ---- build bucketed CSR (reused by both spmm layers) + weight prep ----
    hipMemsetAsync(bcnt, 0, NBUCK * sizeof(int), stream);
    prep_weights<<<32, 256, 0, stream>>>(W1, W2, Wc, W1t, W2t, Wct);
    part_a<<<grid_a, 256, 0, stream>>>(erow, ecol, eval, bcnt, tmp);
    part_b<<<NBUCK, 256, 0, stream>>>(bcnt, tmp, rowmeta);

    // ---- layer 1 ----
    gemm1_mfma<<<tile_grid, 256, 0, stream>>>(x, W1t, b1, bufA);
    spmm_csr<<<spmm_grid, 256, 0, stream>>>(rowmeta, tmp, bufA, bufB);
    // ---- layer 2 (ReLU fused into gemm2 A-load) ----
    gemm2_mfma<<<tile_grid, 256, 0, stream>>>(bufB, W2t, b2, bufA);
    spmm_csr<<<spmm_grid, 256, 0, stream>>>(rowmeta, tmp, bufA, bufB);
    // ---- classifier + log-softmax ----
    classify_mfma<<<tile_grid, 256, 0, stream>>>(bufB, Wct, bc, out);
}

// Round 6
// 280.284 us; speedup vs baseline: 10.7777x; 1.0754x over previous
//
#include <hip/hip_runtime.h>

#define N_NODES   100000
#define N_EDGES   1600000
#define IN_DIM    128
#define HID_DIM   64
#define N_CLASSES 40
#define NCPAD     48       // classes padded to 3 MFMA tiles

#define NBUCK 782          // ceil(100000 / 128) coarse buckets, bucket = row >> 7
#define BCAP  2816         // bucket capacity incl. pad-to-8 (mean 2496, sigma ~52 -> 6 sigma)
#define EPB   6400         // edges per block in pass A; 250 * 6400 == N_EDGES exactly

typedef __attribute__((ext_vector_type(8))) short bf16x8;
typedef __attribute__((ext_vector_type(4))) float f32x4;

__device__ inline short f2bf(float f) {
    unsigned u = __float_as_uint(f);
    unsigned r = (u + 0x7FFFu + ((u >> 16) & 1u)) >> 16;   // round-to-nearest-even
    return (short)r;
}
__device__ inline float bf2f(unsigned short s) {
    return __uint_as_float(((unsigned)s) << 16);
}
__device__ inline float bflo(unsigned w) { return __uint_as_float(w << 16); }
__device__ inline float bfhi(unsigned w) { return __uint_as_float(w & 0xFFFF0000u); }

// ---------------- weight prep ----------------
__global__ __launch_bounds__(256) void prep_weights(const float* __restrict__ W1,
                                                    const float* __restrict__ W2,
                                                    const float* __restrict__ Wc,
                                                    short* __restrict__ W1t,
                                                    short* __restrict__ W2t,
                                                    short* __restrict__ Wct) {
    for (int i = blockIdx.x * 256 + threadIdx.x; i < IN_DIM * HID_DIM; i += gridDim.x * 256) {
        int n = i >> 7, k = i & 127;
        W1t[i] = f2bf(W1[k * HID_DIM + n]);
    }
    for (int i = blockIdx.x * 256 + threadIdx.x; i < HID_DIM * HID_DIM; i += gridDim.x * 256) {
        int n = i >> 6, k = i & 63;
        W2t[i] = f2bf(W2[k * HID_DIM + n]);
    }
    for (int i = blockIdx.x * 256 + threadIdx.x; i < NCPAD * HID_DIM; i += gridDim.x * 256) {
        int c = i >> 6, k = i & 63;
        Wct[i] = (c < N_CLASSES) ? f2bf(Wc[k * N_CLASSES + c]) : 0;
    }
}

// ---------------- GEMM1 (MFMA): hbf[n,64] = bf16(x[n,128] @ W1 + b1) ----------------
__global__ __launch_bounds__(256) void gemm1_mfma(const float* __restrict__ x,
                                                  const short* __restrict__ W1t,
                                                  const float* __restrict__ b1,
                                                  unsigned short* __restrict__ out) {
    int wave = threadIdx.x >> 6;
    int lane = threadIdx.x & 63;
    int node0 = blockIdx.x * 64 + wave * 16;
    if (node0 >= N_NODES) return;
    int m = lane & 15;
    int q = lane >> 4;
    const float* xrow = x + (size_t)(node0 + m) * IN_DIM;
    f32x4 acc0 = {0,0,0,0}, acc1 = {0,0,0,0}, acc2 = {0,0,0,0}, acc3 = {0,0,0,0};
#pragma unroll
    for (int kb = 0; kb < 4; ++kb) {
        int k0 = kb * 32 + q * 8;
        float4 a0 = *(const float4*)(xrow + k0);
        float4 a1 = *(const float4*)(xrow + k0 + 4);
        bf16x8 af;
        af[0]=f2bf(a0.x); af[1]=f2bf(a0.y); af[2]=f2bf(a0.z); af[3]=f2bf(a0.w);
        af[4]=f2bf(a1.x); af[5]=f2bf(a1.y); af[6]=f2bf(a1.z); af[7]=f2bf(a1.w);
        bf16x8 bf0 = *(const bf16x8*)(W1t + ( 0 + m) * IN_DIM + k0);
        bf16x8 bf1 = *(const bf16x8*)(W1t + (16 + m) * IN_DIM + k0);
        bf16x8 bf2 = *(const bf16x8*)(W1t + (32 + m) * IN_DIM + k0);
        bf16x8 bf3 = *(const bf16x8*)(W1t + (48 + m) * IN_DIM + k0);
        acc0 = __builtin_amdgcn_mfma_f32_16x16x32_bf16(af, bf0, acc0, 0, 0, 0);
        acc1 = __builtin_amdgcn_mfma_f32_16x16x32_bf16(af, bf1, acc1, 0, 0, 0);
        acc2 = __builtin_amdgcn_mfma_f32_16x16x32_bf16(af, bf2, acc2, 0, 0, 0);
        acc3 = __builtin_amdgcn_mfma_f32_16x16x32_bf16(af, bf3, acc3, 0, 0, 0);
    }
    f32x4 accs[4] = {acc0, acc1, acc2, acc3};
#pragma unroll
    for (int t = 0; t < 4; ++t) {
        float bias = b1[t * 16 + m];
#pragma unroll
        for (int r = 0; r < 4; ++r) {
            int node = node0 + q * 4 + r;            // C/D: col=lane&15, row=q*4+r
            out[(size_t)node * HID_DIM + t * 16 + m] = (unsigned short)f2bf(accs[t][r] + bias);
        }
    }
}

// ---------------- GEMM2 (MFMA): hbf_out[n,64] = bf16(relu(hbf[n,64]) @ W2 + b2) ----------------
__global__ __launch_bounds__(256) void gemm2_mfma(const unsigned short* __restrict__ h,
                                                  const short* __restrict__ W2t,
                                                  const float* __restrict__ b2,
                                                  unsigned short* __restrict__ out) {
    int wave = threadIdx.x >> 6;
    int lane = threadIdx.x & 63;
    int node0 = blockIdx.x * 64 + wave * 16;
    if (node0 >= N_NODES) return;
    int m = lane & 15;
    int q = lane >> 4;
    const unsigned short* hrow = h + (size_t)(node0 + m) * HID_DIM;
    f32x4 acc0 = {0,0,0,0}, acc1 = {0,0,0,0}, acc2 = {0,0,0,0}, acc3 = {0,0,0,0};
#pragma unroll
    for (int kb = 0; kb < 2; ++kb) {
        int k0 = kb * 32 + q * 8;
        bf16x8 af = *(const bf16x8*)(hrow + k0);
#pragma unroll
        for (int j = 0; j < 8; ++j)
            af[j] = ((unsigned short)af[j] & 0x8000u) ? 0 : af[j];   // bf16 ReLU
        bf16x8 bf0 = *(const bf16x8*)(W2t + ( 0 + m) * HID_DIM + k0);
        bf16x8 bf1 = *(const bf16x8*)(W2t + (16 + m) * HID_DIM + k0);
        bf16x8 bf2 = *(const bf16x8*)(W2t + (32 + m) * HID_DIM + k0);
        bf16x8 bf3 = *(const bf16x8*)(W2t + (48 + m) * HID_DIM + k0);
        acc0 = __builtin_amdgcn_mfma_f32_16x16x32_bf16(af, bf0, acc0, 0, 0, 0);
        acc1 = __builtin_amdgcn_mfma_f32_16x16x32_bf16(af, bf1, acc1, 0, 0, 0);
        acc2 = __builtin_amdgcn_mfma_f32_16x16x32_bf16(af, bf2, acc2, 0, 0, 0);
        acc3 = __builtin_amdgcn_mfma_f32_16x16x32_bf16(af, bf3, acc3, 0, 0, 0);
    }
    f32x4 accs[4] = {acc0, acc1, acc2, acc3};
#pragma unroll
    for (int t = 0; t < 4; ++t) {
        float bias = b2[t * 16 + m];
#pragma unroll
        for (int r = 0; r < 4; ++r) {
            int node = node0 + q * 4 + r;
            out[(size_t)node * HID_DIM + t * 16 + m] = (unsigned short)f2bf(accs[t][r] + bias);
        }
    }
}

// ---------------- Pass A: partition edges into 782 coarse buckets (row >> 7) ----------------
__global__ __launch_bounds__(256) void part_a(const int* __restrict__ erow,
                                              const int* __restrict__ ecol,
                                              const float* __restrict__ eval,
                                              int* __restrict__ bcnt,
                                              int2* __restrict__ tmp) {
    __shared__ int srow[EPB];        // 25.6 KB
    __shared__ int hist[NBUCK];
    __shared__ int gbase[NBUCK];
    __shared__ int cur[NBUCK];
    int e0 = blockIdx.x * EPB;
    for (int i = threadIdx.x; i < NBUCK; i += 256) { hist[i] = 0; cur[i] = 0; }
    __syncthreads();
    for (int i = threadIdx.x; i < EPB; i += 256) {
        int e = e0 + i;
        int r = (e < N_EDGES) ? erow[e] : -1;
        srow[i] = r;
        if (r >= 0) atomicAdd(&hist[r >> 7], 1);
    }
    __syncthreads();
    for (int i = threadIdx.x; i < NBUCK; i += 256) {
        int n = hist[i];
        gbase[i] = n ? atomicAdd(&bcnt[i], n) : 0;
    }
    __syncthreads();
    for (int i = threadIdx.x; i < EPB; i += 256) {
        int r = srow[i];
        if (r < 0) continue;
        int e = e0 + i;
        int b = r >> 7;
        int slot = gbase[b] + atomicAdd(&cur[b], 1);
        if (slot < BCAP)
            tmp[(size_t)b * BCAP + slot] =
                make_int2(((r & 127) << 17) | ecol[e], __float_as_int(eval[e]));
    }
}

// ---------------- Pass B: sort bucket by local row, pad each row to mult-of-8, col *= 64 ----------------
__global__ __launch_bounds__(256) void part_b(const int* __restrict__ bcnt,
                                              int2* __restrict__ tmp,
                                              int2* __restrict__ rowmeta) {
    __shared__ int2 ein[BCAP];       // 22.5 KB
    __shared__ int2 eout[BCAP];      // 22.5 KB
    __shared__ int hist[128], pad[128], basep[128], cur[128], scan[128];
    int b = blockIdx.x;
    int nb = bcnt[b]; if (nb > BCAP) nb = BCAP;
    for (int i = threadIdx.x; i < nb; i += 256) ein[i] = tmp[(size_t)b * BCAP + i];
    if (threadIdx.x < 128) { hist[threadIdx.x] = 0; cur[threadIdx.x] = 0; }
    __syncthreads();
    for (int i = threadIdx.x; i < nb; i += 256)
        atomicAdd(&hist[(ein[i].x >> 17) & 127], 1);
    __syncthreads();
    if (threadIdx.x < 128) {
        pad[threadIdx.x] = (hist[threadIdx.x] + 7) & ~7;   // pad to multiple of 8
        scan[threadIdx.x] = pad[threadIdx.x];
    }
    __syncthreads();
    for (int off = 1; off < 128; off <<= 1) {
        int t = 0;
        if (threadIdx.x < 128 && threadIdx.x >= off) t = scan[threadIdx.x - off];
        __syncthreads();
        if (threadIdx.x < 128) scan[threadIdx.x] += t;
        __syncthreads();
    }
    if (threadIdx.x < 128) basep[threadIdx.x] = scan[threadIdx.x] - pad[threadIdx.x];
    __syncthreads();
    int ntot = scan[127]; if (ntot > BCAP) ntot = BCAP;
    // scatter real edges (strip local row, pre-scale col by 64)
    for (int i = threadIdx.x; i < nb; i += 256) {
        int lr = (ein[i].x >> 17) & 127;
        int p = basep[lr] + atomicAdd(&cur[lr], 1);
        if (p < BCAP) eout[p] = make_int2((ein[i].x & 0x1FFFF) << 6, ein[i].y);
    }
    __syncthreads();
    // fill padding with (col64=0, val=0)
    if (threadIdx.x < 128) {
        int pe = basep[threadIdx.x] + pad[threadIdx.x];
        for (int p = basep[threadIdx.x] + hist[threadIdx.x]; p < pe && p < BCAP; ++p)
            eout[p] = make_int2(0, 0);
    }
    __syncthreads();
    for (int i = threadIdx.x; i < ntot; i += 256) tmp[(size_t)b * BCAP + i] = eout[i];
    if (threadIdx.x < 128) {
        int r = b * 128 + threadIdx.x;
        if (r < N_NODES)
            rowmeta[r] = make_int2(b * BCAP + basep[threadIdx.x], pad[threadIdx.x]);
    }
}

// ---------------- SpMM v2: one wave per row; 8 edges per gather instruction ----------------
// lane = (g = lane>>3: edge subgroup, dq = lane&7: dim octet). 16 B/lane dwordx4 gathers.
__global__ __launch_bounds__(256) void spmm_csr(const int2* __restrict__ rowmeta,
                                                const int2* __restrict__ ecv,
                                                const unsigned short* __restrict__ dense,
                                                unsigned short* __restrict__ out) {
    int r = blockIdx.x * 4 + (threadIdx.x >> 6);
    if (r >= N_NODES) return;
    int lane = threadIdx.x & 63;
    int g  = lane >> 3;
    int dq = lane & 7;
    int2 meta = rowmeta[r];
    int rs   = __builtin_amdgcn_readfirstlane(meta.x);
    int degp = __builtin_amdgcn_readfirstlane(meta.y);   // padded degree (multiple of 8)
    float a0=0,a1=0,a2=0,a3=0,a4=0,a5=0,a6=0,a7=0;
    if (degp > 0) {
        // preload this row's edge metadata: lane i -> edge rs+i (coalesced 512 B)
        int2 em = ecv[rs + (lane < degp ? lane : degp - 1)];
        int iters = degp >> 3; if (iters > 8) iters = 8;
        int   col = __shfl(em.x, g);
        float v   = __shfl(__int_as_float(em.y), g);
        uint4 d = *(const uint4*)(dense + (size_t)col + (dq << 3));
        for (int t = 0; t < iters; ++t) {
            int ni = (t * 8 + 8 + g) & 63;
            int   ncol = __shfl(em.x, ni);
            float nv   = __shfl(__int_as_float(em.y), ni);
            uint4 nd = make_uint4(0, 0, 0, 0);
            if (t + 1 < iters) nd = *(const uint4*)(dense + (size_t)ncol + (dq << 3));
            a0 = fmaf(v, bflo(d.x), a0);  a1 = fmaf(v, bfhi(d.x), a1);
            a2 = fmaf(v, bflo(d.y), a2);  a3 = fmaf(v, bfhi(d.y), a3);
            a4 = fmaf(v, bflo(d.z), a4);  a5 = fmaf(v, bfhi(d.z), a5);
            a6 = fmaf(v, bflo(d.w), a6);  a7 = fmaf(v, bfhi(d.w), a7);
            d = nd; col = ncol; v = nv;
        }
        // tail for degp > 64 (essentially never with Poisson(16) rows)
        for (int e = rs + 64; e < rs + degp; ++e) {
            int2 ee = ecv[e];
            if (g == 0) {
                float tv = __int_as_float(ee.y);
                uint4 td = *(const uint4*)(dense + (size_t)ee.x + (dq << 3));
                a0 = fmaf(tv, bflo(td.x), a0);  a1 = fmaf(tv, bfhi(td.x), a1);
                a2 = fmaf(tv, bflo(td.y), a2);  a3 = fmaf(tv, bfhi(td.y), a3);
                a4 = fmaf(tv, bflo(td.z), a4);  a5 = fmaf(tv, bfhi(td.z), a5);
                a6 = fmaf(tv, bflo(td.w), a6);  a7 = fmaf(tv, bfhi(td.w), a7);
            }
        }
    }
    // butterfly-reduce the 8 edge-subgroups (xor 8, 16, 32)
#pragma unroll
    for (int off = 8; off < 64; off <<= 1) {
        a0 += __shfl_xor(a0, off); a1 += __shfl_xor(a1, off);
        a2 += __shfl_xor(a2, off); a3 += __shfl_xor(a3, off);
        a4 += __shfl_xor(a4, off); a5 += __shfl_xor(a5, off);
        a6 += __shfl_xor(a6, off); a7 += __shfl_xor(a7, off);
    }
    if (lane < 8) {
        uint4 o;
        o.x = (unsigned short)f2bf(a0) | ((unsigned)(unsigned short)f2bf(a1) << 16);
        o.y = (unsigned short)f2bf(a2) | ((unsigned)(unsigned short)f2bf(a3) << 16);
        o.z = (unsigned short)f2bf(a4) | ((unsigned)(unsigned short)f2bf(a5) << 16);
        o.w = (unsigned short)f2bf(a6) | ((unsigned)(unsigned short)f2bf(a7) << 16);
        *(uint4*)(out + (size_t)r * HID_DIM + lane * 8) = o;
    }
}

// ---------------- Classifier (MFMA): out = log_softmax(h @ Wc + bc) ----------------
#define SLOGW 49
__global__ __launch_bounds__(256) void classify_mfma(const unsigned short* __restrict__ h,
                                                     const short* __restrict__ Wct,
                                                     const float* __restrict__ bc,
                                                     float* __restrict__ out) {
    __shared__ float slog[64 * SLOGW];
    __shared__ float smax[64], slse[64];
    int wave = threadIdx.x >> 6;
    int lane = threadIdx.x & 63;
    int node0 = blockIdx.x * 64;
    int wnode0 = node0 + wave * 16;
    int m = lane & 15;
    int q = lane >> 4;
    int arow = wnode0 + m; if (arow >= N_NODES) arow = N_NODES - 1;
    const unsigned short* hrow = h + (size_t)arow * HID_DIM;
    f32x4 acc0 = {0,0,0,0}, acc1 = {0,0,0,0}, acc2 = {0,0,0,0};
#pragma unroll
    for (int kb = 0; kb < 2; ++kb) {
        int k0 = kb * 32 + q * 8;
        bf16x8 af = *(const bf16x8*)(hrow + k0);
        bf16x8 bf0 = *(const bf16x8*)(Wct + ( 0 + m) * HID_DIM + k0);
        bf16x8 bf1 = *(const bf16x8*)(Wct + (16 + m) * HID_DIM + k0);
        bf16x8 bf2 = *(const bf16x8*)(Wct + (32 + m) * HID_DIM + k0);
        acc0 = __builtin_amdgcn_mfma_f32_16x16x32_bf16(af, bf0, acc0, 0, 0, 0);
        acc1 = __builtin_amdgcn_mfma_f32_16x16x32_bf16(af, bf1, acc1, 0, 0, 0);
        acc2 = __builtin_amdgcn_mfma_f32_16x16x32_bf16(af, bf2, acc2, 0, 0, 0);
    }
    f32x4 accs[3] = {acc0, acc1, acc2};
#pragma unroll
    for (int t = 0; t < 3; ++t) {
        int cls = t * 16 + m;
        float bias = (cls < N_CLASSES) ? bc[cls] : 0.f;
#pragma unroll
        for (int r = 0; r < 4; ++r) {
            int nl = wave * 16 + q * 4 + r;
            slog[nl * SLOGW + cls] = accs[t][r] + bias;
        }
    }
    __syncthreads();
    if (threadIdx.x < 64) {
        int nl = threadIdx.x;
        float mx = -1e30f;
        for (int c = 0; c < N_CLASSES; ++c) mx = fmaxf(mx, slog[nl * SLOGW + c]);
        float s = 0.f;
        for (int c = 0; c < N_CLASSES; ++c) s += expf(slog[nl * SLOGW + c] - mx);
        smax[nl] = mx;
        slse[nl] = logf(s);
    }
    __syncthreads();
    for (int i = threadIdx.x; i < 64 * N_CLASSES; i += 256) {
        long long gi = (long long)node0 * N_CLASSES + i;
        if (gi < (long long)N_NODES * N_CLASSES) {
            int nl = i / N_CLASSES, c = i - nl * N_CLASSES;
            out[gi] = slog[nl * SLOGW + c] - smax[nl] - slse[nl];
        }
    }
}

extern "C" void kernel_launch(void* const* d_in, const int* in_sizes, int n_in,
                              void* d_out, int out_size, void* d_ws, size_t ws_size,
                              hipStream_t stream) {
    const float* x    = (const float*)d_in[0];
    const int*   erow = (const int*)  d_in[1];
    const int*   ecol = (const int*)  d_in[2];
    const float* eval = (const float*)d_in[3];
    const float* W1   = (const float*)d_in[4];
    const float* b1   = (const float*)d_in[5];
    const float* W2   = (const float*)d_in[6];
    const float* b2   = (const float*)d_in[7];
    const float* Wc   = (const float*)d_in[8];
    const float* bc   = (const float*)d_in[9];
    float* out = (float*)d_out;

    // ---- workspace layout ----
    char* ws = (char*)d_ws;
    size_t off = 0;
    auto alloc = [&](size_t bytes) { char* p = ws + off; off += (bytes + 255) & ~(size_t)255; return p; };
    unsigned short* bufA = (unsigned short*)alloc((size_t)N_NODES * HID_DIM * sizeof(short)); // 12.8 MB
    unsigned short* bufB = (unsigned short*)alloc((size_t)N_NODES * HID_DIM * sizeof(short)); // 12.8 MB
    int2*  tmp     = (int2*) alloc((size_t)NBUCK * BCAP * sizeof(int2));       // 17.6 MB
    int2*  rowmeta = (int2*) alloc((size_t)N_NODES * sizeof(int2));            // 0.8 MB
    int*   bcnt    = (int*)  alloc(NBUCK * sizeof(int));
    short* W1t     = (short*)alloc((size_t)IN_DIM * HID_DIM * sizeof(short));
    short* W2t     = (short*)alloc((size_t)HID_DIM * HID_DIM * sizeof(short));
    short* Wct     = (short*)alloc((size_t)NCPAD * HID_DIM * sizeof(short));

    const int tile_grid = (N_NODES + 63) / 64;     // 1563
    const int spmm_grid = (N_NODES + 3) / 4;
    const int grid_a    = (N_EDGES + EPB - 1) / EPB;   // 250

    // ---- build bucketed padded CSR (reused by both spmm layers) + weight prep ----
    hipMemsetAsync(bcnt, 0, NBUCK * sizeof(int), stream);
    prep_weights<<<32, 256, 0, stream>>>(W1, W2, Wc, W1t, W2t, Wct);
    part_a<<<grid_a, 256, 0, stream>>>(erow, ecol, eval, bcnt, tmp);
    part_b<<<NBUCK, 256, 0, stream>>>(bcnt, tmp, rowmeta);

    // ---- layer 1 ----
    gemm1_mfma<<<tile_grid, 256, 0, stream>>>(x, W1t, b1, bufA);
    spmm_csr<<<spmm_grid, 256, 0, stream>>>(rowmeta, tmp, bufA, bufB);
    // ---- layer 2 (ReLU fused into gemm2 A-load) ----
    gemm2_mfma<<<tile_grid, 256, 0, stream>>>(bufB, W2t, b2, bufA);
    spmm_csr<<<spmm_grid, 256, 0, stream>>>(rowmeta, tmp, bufA, bufB);
    // ---- classifier + log-softmax ----
    classify_mfma<<<tile_grid, 256, 0, stream>>>(bufB, Wct, bc, out);
}